// Round 1
// baseline (1439.345 us; speedup 1.0000x reference)
//
#include <hip/hip_runtime.h>
#include <hip/hip_bf16.h>

#define B_ 4
#define H_ 16
#define S_ 2048
#define D_ 64

// LDS strides (in shorts). 72*2=144 B rows: 16B-aligned, odd word-stride (36)
// for decent bank spread on b128 reads.
#define KS 72
#define PS 72

typedef __attribute__((ext_vector_type(8))) short bf16x8;
typedef __attribute__((ext_vector_type(4))) float f32x4;

__device__ __forceinline__ short f2bf(float x) {
    __hip_bfloat16 h = __float2bfloat16(x);
    union { __hip_bfloat16 h; short s; } u;
    u.h = h;
    return u.s;
}

__global__ __launch_bounds__(256, 2)
void attn_kernel(const float* __restrict__ Q, const float* __restrict__ K,
                 const float* __restrict__ V, const int* __restrict__ mask,
                 float* __restrict__ out, float* __restrict__ wout)
{
    __shared__ __align__(16) short Ksh[64 * KS];      // K[key][d]  bf16
    __shared__ __align__(16) short Vsh[64 * KS];      // V^T: Vsh[d][key] bf16
    __shared__ __align__(16) short Psh[4][16 * PS];   // per-wave P[q][key] bf16
    __shared__ int msh[64];

    const int tid  = threadIdx.x;
    const int wave = tid >> 6;
    const int lane = tid & 63;
    const int quad = lane >> 4;
    const int col  = lane & 15;

    const int bh = blockIdx.x >> 5;       // head index 0..63
    const int qt = blockIdx.x & 31;       // q-tile within head
    const int q0 = qt * 64 + wave * 16;   // this wave's first q row

    const float* Qh = Q + (size_t)bh * S_ * D_;
    const float* Kh = K + (size_t)bh * S_ * D_;
    const float* Vh = V + (size_t)bh * S_ * D_;
    const int*   mk = mask + (size_t)(bh >> 4) * S_;   // broadcast over h,q
    float* outh = out  + (size_t)bh * S_ * D_;
    float* wh   = wout + (size_t)bh * S_ * S_;

    // ---- Q fragments (A-layout: m=col, k=quad*8+j), resident all kernel ----
    bf16x8 qf[2];
    {
        const float* qp = Qh + (size_t)(q0 + col) * D_ + quad * 8;
        #pragma unroll
        for (int c = 0; c < 2; ++c) {
            bf16x8 v;
            #pragma unroll
            for (int j = 0; j < 8; ++j) v[j] = f2bf(qp[c * 32 + j]);
            qf[c] = v;
        }
    }

    // staging map: thread -> (key row, 16-wide d chunk)
    const int srow = tid >> 2;        // 0..63
    const int sd0  = (tid & 3) * 16;  // 0,16,32,48

    // =========================== PASS 1: rowsums ===========================
    float rsum[4] = {0.f, 0.f, 0.f, 0.f};
    for (int kt = 0; kt < S_; kt += 64) {
        __syncthreads();
        {
            const float4* kp4 = (const float4*)(Kh + (size_t)(kt + srow) * D_ + sd0);
            float4 a = kp4[0], b = kp4[1], c = kp4[2], d = kp4[3];
            bf16x8 lo, hi;
            lo[0]=f2bf(a.x); lo[1]=f2bf(a.y); lo[2]=f2bf(a.z); lo[3]=f2bf(a.w);
            lo[4]=f2bf(b.x); lo[5]=f2bf(b.y); lo[6]=f2bf(b.z); lo[7]=f2bf(b.w);
            hi[0]=f2bf(c.x); hi[1]=f2bf(c.y); hi[2]=f2bf(c.z); hi[3]=f2bf(c.w);
            hi[4]=f2bf(d.x); hi[5]=f2bf(d.y); hi[6]=f2bf(d.z); hi[7]=f2bf(d.w);
            *(bf16x8*)&Ksh[srow * KS + sd0]     = lo;
            *(bf16x8*)&Ksh[srow * KS + sd0 + 8] = hi;
            if (tid < 64) msh[tid] = mk[kt + tid];
        }
        __syncthreads();
        #pragma unroll
        for (int sub = 0; sub < 4; ++sub) {
            const short* kb = &Ksh[(sub * 16 + col) * KS + quad * 8];
            bf16x8 kf0 = *(const bf16x8*)kb;
            bf16x8 kf1 = *(const bf16x8*)(kb + 32);
            f32x4 acc = {0.f, 0.f, 0.f, 0.f};
            acc = __builtin_amdgcn_mfma_f32_16x16x32_bf16(qf[0], kf0, acc, 0, 0, 0);
            acc = __builtin_amdgcn_mfma_f32_16x16x32_bf16(qf[1], kf1, acc, 0, 0, 0);
            const int mv = msh[sub * 16 + col];
            #pragma unroll
            for (int i = 0; i < 4; ++i) {
                float p = (mv == 1) ? 0.f : __expf(acc[i] * 0.125f);
                rsum[i] += p;
            }
        }
    }
    // reduce rowsums across the 16 col-lanes (rows = quad*4+i identical there)
    #pragma unroll
    for (int off = 1; off < 16; off <<= 1) {
        #pragma unroll
        for (int i = 0; i < 4; ++i) rsum[i] += __shfl_xor(rsum[i], off);
    }
    float rinv[4];
    #pragma unroll
    for (int i = 0; i < 4; ++i) rinv[i] = 1.0f / rsum[i];

    // ================= PASS 2: weights write + PV accumulate =================
    f32x4 oacc[4];
    #pragma unroll
    for (int nt = 0; nt < 4; ++nt) oacc[nt] = (f32x4){0.f, 0.f, 0.f, 0.f};

    short* pw = Psh[wave];
    for (int kt = 0; kt < S_; kt += 64) {
        __syncthreads();
        {
            const float4* kp4 = (const float4*)(Kh + (size_t)(kt + srow) * D_ + sd0);
            float4 a = kp4[0], b = kp4[1], c = kp4[2], d = kp4[3];
            bf16x8 lo, hi;
            lo[0]=f2bf(a.x); lo[1]=f2bf(a.y); lo[2]=f2bf(a.z); lo[3]=f2bf(a.w);
            lo[4]=f2bf(b.x); lo[5]=f2bf(b.y); lo[6]=f2bf(b.z); lo[7]=f2bf(b.w);
            hi[0]=f2bf(c.x); hi[1]=f2bf(c.y); hi[2]=f2bf(c.z); hi[3]=f2bf(c.w);
            hi[4]=f2bf(d.x); hi[5]=f2bf(d.y); hi[6]=f2bf(d.z); hi[7]=f2bf(d.w);
            *(bf16x8*)&Ksh[srow * KS + sd0]     = lo;
            *(bf16x8*)&Ksh[srow * KS + sd0 + 8] = hi;

            const float4* vp4 = (const float4*)(Vh + (size_t)(kt + srow) * D_ + sd0);
            float4 va = vp4[0], vb = vp4[1], vc = vp4[2], vd = vp4[3];
            float vv[16] = {va.x, va.y, va.z, va.w, vb.x, vb.y, vb.z, vb.w,
                            vc.x, vc.y, vc.z, vc.w, vd.x, vd.y, vd.z, vd.w};
            #pragma unroll
            for (int j = 0; j < 16; ++j)
                Vsh[(sd0 + j) * KS + srow] = f2bf(vv[j]);   // transpose: Vsh[d][key]

            if (tid < 64) msh[tid] = mk[kt + tid];
        }
        __syncthreads();
        #pragma unroll
        for (int sub = 0; sub < 4; ++sub) {
            const short* kb = &Ksh[(sub * 16 + col) * KS + quad * 8];
            bf16x8 kf0 = *(const bf16x8*)kb;
            bf16x8 kf1 = *(const bf16x8*)(kb + 32);
            f32x4 acc = {0.f, 0.f, 0.f, 0.f};
            acc = __builtin_amdgcn_mfma_f32_16x16x32_bf16(qf[0], kf0, acc, 0, 0, 0);
            acc = __builtin_amdgcn_mfma_f32_16x16x32_bf16(qf[1], kf1, acc, 0, 0, 0);
            const int mv = msh[sub * 16 + col];
            #pragma unroll
            for (int i = 0; i < 4; ++i) {
                float p = (mv == 1) ? 0.f : __expf(acc[i] * 0.125f) * rinv[i];
                // C-layout: row = quad*4+i, col = key
                wh[(size_t)(q0 + quad * 4 + i) * S_ + kt + sub * 16 + col] = p;
                pw[(quad * 4 + i) * PS + sub * 16 + col] = f2bf(p);
            }
        }
        __syncthreads();  // P tile visible (and ordering for Vsh reads)
        #pragma unroll
        for (int c = 0; c < 2; ++c) {
            // P in A-layout: m=col, k = c*32 + quad*8 + j
            bf16x8 af = *(const bf16x8*)&pw[col * PS + c * 32 + quad * 8];
            #pragma unroll
            for (int nt = 0; nt < 4; ++nt) {
                // V in B-layout: n = nt*16+col (=d), k = c*32+quad*8+j (=key)
                bf16x8 vf = *(const bf16x8*)&Vsh[(nt * 16 + col) * KS + c * 32 + quad * 8];
                oacc[nt] = __builtin_amdgcn_mfma_f32_16x16x32_bf16(af, vf, oacc[nt], 0, 0, 0);
            }
        }
    }

    // epilogue: O already normalized (P was normalized before PV)
    #pragma unroll
    for (int nt = 0; nt < 4; ++nt) {
        #pragma unroll
        for (int i = 0; i < 4; ++i)
            outh[(size_t)(q0 + quad * 4 + i) * D_ + nt * 16 + col] = oacc[nt][i];
    }
}

extern "C" void kernel_launch(void* const* d_in, const int* in_sizes, int n_in,
                              void* d_out, int out_size, void* d_ws, size_t ws_size,
                              hipStream_t stream) {
    const float* Q    = (const float*)d_in[0];
    const float* K    = (const float*)d_in[1];
    const float* V    = (const float*)d_in[2];
    const int*   mask = (const int*)d_in[3];
    float* out  = (float*)d_out;
    float* wout = out + (size_t)B_ * H_ * S_ * D_;   // outputs concatenated: O then W

    dim3 grid(B_ * H_ * S_ / 64);   // 2048 blocks, 64 q-rows each
    attn_kernel<<<grid, 256, 0, stream>>>(Q, K, V, mask, out, wout);
}